// Round 1
// 7625.468 us; speedup vs baseline: 2.3390x; 2.3390x over previous
//
#include <hip/hip_runtime.h>
#include <math.h>

// MiniGPT forward. B=4 T=1024 D=768 H=12 L=4 DFF=3072 V=32000.
// Round 2: all GEMMs -> bf16 MFMA (v_mfma_f32_16x16x32_bf16), fp32 accumulate.
// Residual stream x, LN stats, softmax stay fp32. Weights transposed+converted
// per layer into reused ws region. 128x128 tile, BK=64, 4 waves, m93-class.

#define V_   32000
#define D_   768
#define H_   12
#define L_   4
#define T_   1024
#define B_   4
#define DFF_ 3072
#define BT_  (B_ * T_)
#define HD_  64
#define LN_EPS 1e-5f

typedef __bf16 bf16x8 __attribute__((ext_vector_type(8)));
typedef float  f32x4  __attribute__((ext_vector_type(4)));
typedef unsigned short us8 __attribute__((ext_vector_type(8)));

__device__ __forceinline__ unsigned short f2bf(float f) {
  unsigned u = __builtin_bit_cast(unsigned, f);
  u += 0x7fffu + ((u >> 16) & 1u);          // RNE
  return (unsigned short)(u >> 16);
}
__device__ __forceinline__ float bf2f(unsigned short h) {
  unsigned u = ((unsigned)h) << 16;
  return __builtin_bit_cast(float, u);
}

// ---------------------------------------------------------------------------
// Embedding: x[b,t,:] = tok_emb[idx[b,t],:] + pos_emb[t,:]   (fp32)
// ---------------------------------------------------------------------------
__global__ __launch_bounds__(256) void embed_k(
    const int* __restrict__ idx, const float* __restrict__ tok,
    const float* __restrict__ pos, float* __restrict__ x) {
  int i = blockIdx.x * 256 + threadIdx.x;
  if (i >= BT_ * D_) return;
  int row = i / D_;
  int d   = i - row * D_;
  int t   = row & (T_ - 1);
  x[i] = tok[(size_t)idx[row] * D_ + d] + pos[t * D_ + d];
}

// ---------------------------------------------------------------------------
// LayerNorm: fp32 in, bf16 out. One 256-thread block per row.
// ---------------------------------------------------------------------------
__global__ __launch_bounds__(256) void ln_k(
    const float* __restrict__ x, const float* __restrict__ g,
    const float* __restrict__ b, unsigned short* __restrict__ out) {
  int row = blockIdx.x;
  const float* xr = x + (size_t)row * D_;
  unsigned short* orow = out + (size_t)row * D_;
  int tid = threadIdx.x;

  float s = 0.f, ss = 0.f;
  for (int i = tid; i < D_; i += 256) {
    float t = xr[i];
    s += t; ss += t * t;
  }
  for (int off = 32; off; off >>= 1) {
    s  += __shfl_xor(s, off, 64);
    ss += __shfl_xor(ss, off, 64);
  }
  __shared__ float sm[2][4];
  int wid = tid >> 6;
  if ((tid & 63) == 0) { sm[0][wid] = s; sm[1][wid] = ss; }
  __syncthreads();
  s  = sm[0][0] + sm[0][1] + sm[0][2] + sm[0][3];
  ss = sm[1][0] + sm[1][1] + sm[1][2] + sm[1][3];

  float mu  = s * (1.f / D_);
  float var = ss * (1.f / D_) - mu * mu;
  float r   = rsqrtf(var + LN_EPS);
  for (int i = tid; i < D_; i += 256)
    orow[i] = f2bf((xr[i] - mu) * r * g[i] + b[i]);
}

// ---------------------------------------------------------------------------
// Weight transpose + convert: in [K][N] f32 -> out [N][K] bf16. 32x32 tiles.
// ---------------------------------------------------------------------------
__global__ __launch_bounds__(256) void tr_k(
    const float* __restrict__ in, unsigned short* __restrict__ out,
    int K, int N) {
  __shared__ float t[32][33];
  int bx = blockIdx.x * 32;   // n
  int by = blockIdx.y * 32;   // k
  int tx = threadIdx.x & 31, ty = threadIdx.x >> 5;   // 32 x 8
#pragma unroll
  for (int i = 0; i < 32; i += 8)
    t[ty + i][tx] = in[(size_t)(by + ty + i) * N + bx + tx];
  __syncthreads();
#pragma unroll
  for (int i = 0; i < 32; i += 8)
    out[(size_t)(bx + ty + i) * K + by + tx] = f2bf(t[tx][ty + i]);
}

// ---------------------------------------------------------------------------
// bf16 MFMA GEMM: C[M,N] = A[M,K] @ B[K,N] (+bias)(relu)(+resid), B given
// transposed as Bt[N][K] bf16. 128x128 tile, BK=64, 256 thr = 4 waves,
// each wave 64x64 = 4x4 fragments of 16x16x32. fp32 accumulate.
// Consistent contiguous-k fragment loads for A and B (k-perm cancels in MFMA).
// M,N,K all multiples of 128/64 here — no guards.
// ---------------------------------------------------------------------------
#define GBM 128
#define GBN 128
#define GBK 64
#define GKP 72   // row stride in bf16: 144B = 9*16B -> 16B-aligned, ~2-way banks

__global__ __launch_bounds__(256) void gemm_bf(
    const unsigned short* __restrict__ A, const unsigned short* __restrict__ Bt,
    const float* __restrict__ bias, const float* __restrict__ resid,
    void* __restrict__ C, int M, int N, int K, int relu, int out_bf16) {
  __shared__ unsigned short As[GBM][GKP];
  __shared__ unsigned short Bs[GBN][GKP];

  int tid  = threadIdx.x;
  int bn   = blockIdx.x * GBN;
  int bm   = blockIdx.y * GBM;
  int w    = tid >> 6, lane = tid & 63;
  int wm   = (w >> 1) * 64, wn = (w & 1) * 64;
  int lr   = lane & 15, lg = lane >> 4;

  f32x4 acc[4][4] = {};

  // staging decomposition: 4 threads per row, 16 bf16 each, rows r0 and r0+64
  int r0 = tid >> 2;
  int c0 = (tid & 3) * 16;
  const unsigned short* Ap = A  + (size_t)(bm + r0) * K + c0;
  const unsigned short* Bp = Bt + (size_t)(bn + r0) * K + c0;
  size_t rowskip = (size_t)64 * K;

  for (int k0 = 0; k0 < K; k0 += GBK) {
    us8 a0 = *(const us8*)(Ap + k0);
    us8 a1 = *(const us8*)(Ap + k0 + 8);
    us8 a2 = *(const us8*)(Ap + k0 + rowskip);
    us8 a3 = *(const us8*)(Ap + k0 + rowskip + 8);
    us8 b0 = *(const us8*)(Bp + k0);
    us8 b1 = *(const us8*)(Bp + k0 + 8);
    us8 b2 = *(const us8*)(Bp + k0 + rowskip);
    us8 b3 = *(const us8*)(Bp + k0 + rowskip + 8);
    *(us8*)&As[r0][c0]          = a0;
    *(us8*)&As[r0][c0 + 8]      = a1;
    *(us8*)&As[r0 + 64][c0]     = a2;
    *(us8*)&As[r0 + 64][c0 + 8] = a3;
    *(us8*)&Bs[r0][c0]          = b0;
    *(us8*)&Bs[r0][c0 + 8]      = b1;
    *(us8*)&Bs[r0 + 64][c0]     = b2;
    *(us8*)&Bs[r0 + 64][c0 + 8] = b3;
    __syncthreads();

#pragma unroll
    for (int ks = 0; ks < GBK; ks += 32) {
      bf16x8 a[4], b[4];
#pragma unroll
      for (int i = 0; i < 4; ++i)
        a[i] = __builtin_bit_cast(bf16x8,
                 *(const us8*)&As[wm + i * 16 + lr][ks + lg * 8]);
#pragma unroll
      for (int j = 0; j < 4; ++j)
        b[j] = __builtin_bit_cast(bf16x8,
                 *(const us8*)&Bs[wn + j * 16 + lr][ks + lg * 8]);
#pragma unroll
      for (int i = 0; i < 4; ++i)
#pragma unroll
        for (int j = 0; j < 4; ++j)
          acc[i][j] = __builtin_amdgcn_mfma_f32_16x16x32_bf16(
              a[i], b[j], acc[i][j], 0, 0, 0);
    }
    __syncthreads();
  }

  // epilogue: D[row=(lane>>4)*4+r][col=lane&15] per fragment (verified m89/m91)
#pragma unroll
  for (int i = 0; i < 4; ++i) {
#pragma unroll
    for (int j = 0; j < 4; ++j) {
      int nn = bn + wn + j * 16 + lr;
      float bv = bias ? bias[nn] : 0.f;
#pragma unroll
      for (int r = 0; r < 4; ++r) {
        int mm = bm + wm + i * 16 + lg * 4 + r;
        float v = acc[i][j][r] + bv;
        if (relu) v = fmaxf(v, 0.f);
        if (resid) v += resid[(size_t)mm * N + nn];
        if (out_bf16)
          ((unsigned short*)C)[(size_t)mm * N + nn] = f2bf(v);
        else
          ((float*)C)[(size_t)mm * N + nn] = v;
      }
    }
  }
}

// ---------------------------------------------------------------------------
// Causal attention, online softmax, fp32 math over bf16 q/k/v.
// qkv fused [BT][3*D]: q at col h*64, k at D + h*64, v at 2D + h*64.
// One wave per (b,h,t). Output att [BT][D] bf16.
// ---------------------------------------------------------------------------
__global__ __launch_bounds__(64) void attn_k(
    const unsigned short* __restrict__ qkv, unsigned short* __restrict__ att) {
  int t = blockIdx.x, h = blockIdx.y, b = blockIdx.z;
  int lane = threadIdx.x;
  const float scale = 0.125f;   // 1/sqrt(64)

  __shared__ float qs[64];
  __shared__ float ks[64][65];
  __shared__ float ps[64];

  const size_t RS = 3 * D_;
  size_t rowq = (size_t)(b * T_ + t) * RS + h * HD_;
  qs[lane] = bf2f(qkv[rowq + lane]);
  __syncthreads();

  float m = -INFINITY, l = 0.f, acc = 0.f;

  for (int s0 = 0; s0 <= t; s0 += 64) {
    int ns = min(64, t - s0 + 1);
    for (int r = 0; r < ns; ++r)
      ks[r][lane] = bf2f(qkv[(size_t)(b * T_ + s0 + r) * RS + D_ + h * HD_ + lane]);
    __syncthreads();

    float sc = -INFINITY;
    if (lane < ns) {
      float d = 0.f;
#pragma unroll
      for (int j = 0; j < 64; ++j) d += qs[j] * ks[lane][j];
      sc = d * scale;
    }
    float mt = sc;
    for (int off = 32; off; off >>= 1) mt = fmaxf(mt, __shfl_xor(mt, off, 64));
    float mnew  = fmaxf(m, mt);
    float alpha = expf(m - mnew);
    float p     = (lane < ns) ? expf(sc - mnew) : 0.f;

    float pl = p;
    for (int off = 32; off; off >>= 1) pl += __shfl_xor(pl, off, 64);
    l   = l * alpha + pl;
    acc = acc * alpha;

    ps[lane] = p;
    __syncthreads();
    for (int s = 0; s < ns; ++s)
      acc += ps[s] * bf2f(qkv[(size_t)(b * T_ + s0 + s) * RS + 2 * D_ + h * HD_ + lane]);
    __syncthreads();
    m = mnew;
  }

  att[(size_t)(b * T_ + t) * D_ + h * HD_ + lane] = f2bf(acc / l);
}

// ---------------------------------------------------------------------------
// launch
// ---------------------------------------------------------------------------
extern "C" void kernel_launch(void* const* d_in, const int* in_sizes, int n_in,
                              void* d_out, int out_size, void* d_ws, size_t ws_size,
                              hipStream_t stream) {
  const int*   idx   = (const int*)  d_in[0];
  const float* tok   = (const float*)d_in[1];
  const float* pos   = (const float*)d_in[2];
  const float* Wq    = (const float*)d_in[3];
  const float* Wk    = (const float*)d_in[4];
  const float* Wv    = (const float*)d_in[5];
  const float* Wp    = (const float*)d_in[6];
  const float* bp    = (const float*)d_in[7];
  const float* ln1g  = (const float*)d_in[8];
  const float* ln1b  = (const float*)d_in[9];
  const float* ln2g  = (const float*)d_in[10];
  const float* ln2b  = (const float*)d_in[11];
  const float* W1    = (const float*)d_in[12];
  const float* b1    = (const float*)d_in[13];
  const float* W2    = (const float*)d_in[14];
  const float* b2    = (const float*)d_in[15];
  const float* lnfg  = (const float*)d_in[16];
  const float* lnfb  = (const float*)d_in[17];
  const float* Wlm   = (const float*)d_in[18];
  const float* blm   = (const float*)d_in[19];
  float* outp = (float*)d_out;

  // workspace layout (~118.4 MB):
  //   x    f32  [BT][D]
  //   xn   bf16 [BT][D]
  //   qkv  bf16 [BT][3D]
  //   att  bf16 [BT][D]
  //   h1   bf16 [BT][DFF]
  //   wt   bf16 max(per-layer 7.08M elems, Wlm^T 24.58M elems)
  float* x = (float*)d_ws;
  unsigned short* xn  = (unsigned short*)(x + (size_t)BT_ * D_);
  unsigned short* qkv = xn  + (size_t)BT_ * D_;
  unsigned short* att = qkv + (size_t)BT_ * 3 * D_;
  unsigned short* h1  = att + (size_t)BT_ * D_;
  unsigned short* wt  = h1  + (size_t)BT_ * DFF_;
  unsigned short* wt_qkv = wt;                                  // [2304][768]
  unsigned short* wt_p   = wt   + (size_t)3 * D_ * D_;          // [768][768]
  unsigned short* wt_1   = wt_p + (size_t)D_ * D_;              // [3072][768]
  unsigned short* wt_2   = wt_1 + (size_t)D_ * DFF_;            // [768][3072]

  dim3 blk(256);
  dim3 g_qkv(3 * D_ / GBN, BT_ / GBM);   // 18 x 32
  dim3 g_d(D_ / GBN, BT_ / GBM);         // 6 x 32
  dim3 g_ff(DFF_ / GBN, BT_ / GBM);      // 24 x 32
  dim3 g_lm(V_ / GBN, BT_ / GBM);        // 250 x 32

  embed_k<<<(BT_ * D_ + 255) / 256, blk, 0, stream>>>(idx, tok, pos, x);

  for (int l = 0; l < L_; ++l) {
    // per-layer weight transpose+convert into reused wt region
    tr_k<<<dim3(D_ / 32, D_ / 32), blk, 0, stream>>>(
        Wq + (size_t)l * D_ * D_, wt_qkv, D_, D_);
    tr_k<<<dim3(D_ / 32, D_ / 32), blk, 0, stream>>>(
        Wk + (size_t)l * D_ * D_, wt_qkv + (size_t)D_ * D_, D_, D_);
    tr_k<<<dim3(D_ / 32, D_ / 32), blk, 0, stream>>>(
        Wv + (size_t)l * D_ * D_, wt_qkv + (size_t)2 * D_ * D_, D_, D_);
    tr_k<<<dim3(D_ / 32, D_ / 32), blk, 0, stream>>>(
        Wp + (size_t)l * D_ * D_, wt_p, D_, D_);
    tr_k<<<dim3(DFF_ / 32, D_ / 32), blk, 0, stream>>>(
        W1 + (size_t)l * D_ * DFF_, wt_1, D_, DFF_);
    tr_k<<<dim3(D_ / 32, DFF_ / 32), blk, 0, stream>>>(
        W2 + (size_t)l * DFF_ * D_, wt_2, DFF_, D_);

    ln_k<<<BT_, blk, 0, stream>>>(x, ln1g + l * D_, ln1b + l * D_, xn);
    // fused qkv projection (no bias in reference)
    gemm_bf<<<g_qkv, blk, 0, stream>>>(xn, wt_qkv, nullptr, nullptr, qkv,
                                       BT_, 3 * D_, D_, 0, 1);
    attn_k<<<dim3(T_, H_, B_), 64, 0, stream>>>(qkv, att);
    // x = x + att @ Wp + bp  (fp32 residual, in-place)
    gemm_bf<<<g_d, blk, 0, stream>>>(att, wt_p, bp + l * D_, x, x,
                                     BT_, D_, D_, 0, 0);

    ln_k<<<BT_, blk, 0, stream>>>(x, ln2g + l * D_, ln2b + l * D_, xn);
    gemm_bf<<<g_ff, blk, 0, stream>>>(xn, wt_1, b1 + l * DFF_, nullptr, h1,
                                      BT_, DFF_, D_, 1, 1);
    gemm_bf<<<g_d, blk, 0, stream>>>(h1, wt_2, b2 + l * D_, x, x,
                                     BT_, D_, DFF_, 0, 0);
  }

  ln_k<<<BT_, blk, 0, stream>>>(x, lnfg, lnfb, xn);
  tr_k<<<dim3(V_ / 32, D_ / 32), blk, 0, stream>>>(Wlm, wt, D_, V_);
  gemm_bf<<<g_lm, blk, 0, stream>>>(xn, wt, blm, nullptr, outp,
                                    BT_, V_, D_, 0, 0);
}

// Round 2
// 2183.118 us; speedup vs baseline: 8.1698x; 3.4929x over previous
//
#include <hip/hip_runtime.h>
#include <math.h>

// MiniGPT forward. B=4 T=1024 D=768 H=12 L=4 DFF=3072 V=32000.
// Round 3: flash-attention on MFMA. GEMMs unchanged (bf16 MFMA, 128x128 tile).
// Residual stream x, LN stats, softmax state stay fp32.

#define V_   32000
#define D_   768
#define H_   12
#define L_   4
#define T_   1024
#define B_   4
#define DFF_ 3072
#define BT_  (B_ * T_)
#define HD_  64
#define LN_EPS 1e-5f

typedef __bf16 bf16x8 __attribute__((ext_vector_type(8)));
typedef float  f32x4  __attribute__((ext_vector_type(4)));
typedef unsigned short us8 __attribute__((ext_vector_type(8)));

__device__ __forceinline__ unsigned short f2bf(float f) {
  unsigned u = __builtin_bit_cast(unsigned, f);
  u += 0x7fffu + ((u >> 16) & 1u);          // RNE
  return (unsigned short)(u >> 16);
}
__device__ __forceinline__ float bf2f(unsigned short h) {
  unsigned u = ((unsigned)h) << 16;
  return __builtin_bit_cast(float, u);
}

// ---------------------------------------------------------------------------
// Embedding: x[b,t,:] = tok_emb[idx[b,t],:] + pos_emb[t,:]   (fp32)
// ---------------------------------------------------------------------------
__global__ __launch_bounds__(256) void embed_k(
    const int* __restrict__ idx, const float* __restrict__ tok,
    const float* __restrict__ pos, float* __restrict__ x) {
  int i = blockIdx.x * 256 + threadIdx.x;
  if (i >= BT_ * D_) return;
  int row = i / D_;
  int d   = i - row * D_;
  int t   = row & (T_ - 1);
  x[i] = tok[(size_t)idx[row] * D_ + d] + pos[t * D_ + d];
}

// ---------------------------------------------------------------------------
// LayerNorm: fp32 in, bf16 out. One 256-thread block per row.
// ---------------------------------------------------------------------------
__global__ __launch_bounds__(256) void ln_k(
    const float* __restrict__ x, const float* __restrict__ g,
    const float* __restrict__ b, unsigned short* __restrict__ out) {
  int row = blockIdx.x;
  const float* xr = x + (size_t)row * D_;
  unsigned short* orow = out + (size_t)row * D_;
  int tid = threadIdx.x;

  float s = 0.f, ss = 0.f;
  for (int i = tid; i < D_; i += 256) {
    float t = xr[i];
    s += t; ss += t * t;
  }
  for (int off = 32; off; off >>= 1) {
    s  += __shfl_xor(s, off, 64);
    ss += __shfl_xor(ss, off, 64);
  }
  __shared__ float sm[2][4];
  int wid = tid >> 6;
  if ((tid & 63) == 0) { sm[0][wid] = s; sm[1][wid] = ss; }
  __syncthreads();
  s  = sm[0][0] + sm[0][1] + sm[0][2] + sm[0][3];
  ss = sm[1][0] + sm[1][1] + sm[1][2] + sm[1][3];

  float mu  = s * (1.f / D_);
  float var = ss * (1.f / D_) - mu * mu;
  float r   = rsqrtf(var + LN_EPS);
  for (int i = tid; i < D_; i += 256)
    orow[i] = f2bf((xr[i] - mu) * r * g[i] + b[i]);
}

// ---------------------------------------------------------------------------
// Weight transpose + convert: in [K][N] f32 -> out [N][K] bf16. 32x32 tiles.
// ---------------------------------------------------------------------------
__global__ __launch_bounds__(256) void tr_k(
    const float* __restrict__ in, unsigned short* __restrict__ out,
    int K, int N) {
  __shared__ float t[32][33];
  int bx = blockIdx.x * 32;   // n
  int by = blockIdx.y * 32;   // k
  int tx = threadIdx.x & 31, ty = threadIdx.x >> 5;   // 32 x 8
#pragma unroll
  for (int i = 0; i < 32; i += 8)
    t[ty + i][tx] = in[(size_t)(by + ty + i) * N + bx + tx];
  __syncthreads();
#pragma unroll
  for (int i = 0; i < 32; i += 8)
    out[(size_t)(bx + ty + i) * K + by + tx] = f2bf(t[tx][ty + i]);
}

// ---------------------------------------------------------------------------
// bf16 MFMA GEMM: C[M,N] = A[M,K] @ B[K,N] (+bias)(relu)(+resid), B given
// transposed as Bt[N][K] bf16. 128x128 tile, BK=64, 256 thr = 4 waves,
// each wave 64x64 = 4x4 fragments of 16x16x32. fp32 accumulate.
// ---------------------------------------------------------------------------
#define GBM 128
#define GBN 128
#define GBK 64
#define GKP 72

__global__ __launch_bounds__(256) void gemm_bf(
    const unsigned short* __restrict__ A, const unsigned short* __restrict__ Bt,
    const float* __restrict__ bias, const float* __restrict__ resid,
    void* __restrict__ C, int M, int N, int K, int relu, int out_bf16) {
  __shared__ unsigned short As[GBM][GKP];
  __shared__ unsigned short Bs[GBN][GKP];

  int tid  = threadIdx.x;
  int bn   = blockIdx.x * GBN;
  int bm   = blockIdx.y * GBM;
  int w    = tid >> 6, lane = tid & 63;
  int wm   = (w >> 1) * 64, wn = (w & 1) * 64;
  int lr   = lane & 15, lg = lane >> 4;

  f32x4 acc[4][4] = {};

  int r0 = tid >> 2;
  int c0 = (tid & 3) * 16;
  const unsigned short* Ap = A  + (size_t)(bm + r0) * K + c0;
  const unsigned short* Bp = Bt + (size_t)(bn + r0) * K + c0;
  size_t rowskip = (size_t)64 * K;

  for (int k0 = 0; k0 < K; k0 += GBK) {
    us8 a0 = *(const us8*)(Ap + k0);
    us8 a1 = *(const us8*)(Ap + k0 + 8);
    us8 a2 = *(const us8*)(Ap + k0 + rowskip);
    us8 a3 = *(const us8*)(Ap + k0 + rowskip + 8);
    us8 b0 = *(const us8*)(Bp + k0);
    us8 b1 = *(const us8*)(Bp + k0 + 8);
    us8 b2 = *(const us8*)(Bp + k0 + rowskip);
    us8 b3 = *(const us8*)(Bp + k0 + rowskip + 8);
    *(us8*)&As[r0][c0]          = a0;
    *(us8*)&As[r0][c0 + 8]      = a1;
    *(us8*)&As[r0 + 64][c0]     = a2;
    *(us8*)&As[r0 + 64][c0 + 8] = a3;
    *(us8*)&Bs[r0][c0]          = b0;
    *(us8*)&Bs[r0][c0 + 8]      = b1;
    *(us8*)&Bs[r0 + 64][c0]     = b2;
    *(us8*)&Bs[r0 + 64][c0 + 8] = b3;
    __syncthreads();

#pragma unroll
    for (int ks = 0; ks < GBK; ks += 32) {
      bf16x8 a[4], b[4];
#pragma unroll
      for (int i = 0; i < 4; ++i)
        a[i] = __builtin_bit_cast(bf16x8,
                 *(const us8*)&As[wm + i * 16 + lr][ks + lg * 8]);
#pragma unroll
      for (int j = 0; j < 4; ++j)
        b[j] = __builtin_bit_cast(bf16x8,
                 *(const us8*)&Bs[wn + j * 16 + lr][ks + lg * 8]);
#pragma unroll
      for (int i = 0; i < 4; ++i)
#pragma unroll
        for (int j = 0; j < 4; ++j)
          acc[i][j] = __builtin_amdgcn_mfma_f32_16x16x32_bf16(
              a[i], b[j], acc[i][j], 0, 0, 0);
    }
    __syncthreads();
  }

#pragma unroll
  for (int i = 0; i < 4; ++i) {
#pragma unroll
    for (int j = 0; j < 4; ++j) {
      int nn = bn + wn + j * 16 + lr;
      float bv = bias ? bias[nn] : 0.f;
#pragma unroll
      for (int r = 0; r < 4; ++r) {
        int mm = bm + wm + i * 16 + lg * 4 + r;
        float v = acc[i][j][r] + bv;
        if (relu) v = fmaxf(v, 0.f);
        if (resid) v += resid[(size_t)mm * N + nn];
        if (out_bf16)
          ((unsigned short*)C)[(size_t)mm * N + nn] = f2bf(v);
        else
          ((float*)C)[(size_t)mm * N + nn] = v;
      }
    }
  }
}

// ---------------------------------------------------------------------------
// Flash attention on MFMA. One block (256 thr = 4 waves) per (b, h, q-tile64).
// qkv fused [BT][3D] bf16: q at h*64, k at D+h*64, v at 2D+h*64.
// Per KV-tile of 64: stage K row-major + V transposed in LDS; QK^T MFMA
// (contiguous-k fragments, same cancel convention as gemm_bf); online softmax
// in registers over the verified C-layout; P->LDS bf16; PV MFMA against Vt.
// Wave w owns q-rows [w*16, w*16+16). fp32 m/l/O state.
// ---------------------------------------------------------------------------
__global__ __launch_bounds__(256) void fattn_k(
    const unsigned short* __restrict__ qkv, unsigned short* __restrict__ att) {
  int qt = blockIdx.x;
  int h  = blockIdx.y, b = blockIdx.z;
  int tid = threadIdx.x;
  int w = tid >> 6, lane = tid & 63;
  int lr = lane & 15, lg = lane >> 4;

  __shared__ unsigned short Ks[64][72];   // [s][hd]
  __shared__ unsigned short Vt[64][72];   // [hd][s]  (transposed V)
  __shared__ unsigned short Ps[64][72];   // [q][s]

  const size_t RS = 3 * D_;
  int q0 = qt * 64;
  size_t base = (size_t)(b * T_) * RS + h * HD_;

  // Q fragments: A row = lr -> q-row w*16+lr; k = ks*32 + lg*8 .. +8
  bf16x8 qf[2];
  {
    const unsigned short* qp = qkv + base + (size_t)(q0 + w * 16 + lr) * RS + lg * 8;
    qf[0] = __builtin_bit_cast(bf16x8, *(const us8*)(qp));
    qf[1] = __builtin_bit_cast(bf16x8, *(const us8*)(qp + 32));
  }

  f32x4 o_acc[4] = {};                 // d-frag j: col d = j*16+lr, row q = w*16+lg*4+r
  float mrow[4], lrow[4];
#pragma unroll
  for (int r = 0; r < 4; ++r) { mrow[r] = -INFINITY; lrow[r] = 0.f; }

  int r0 = tid >> 2;          // staging source row (s)
  int c0 = (tid & 3) * 16;    // staging col (hd)
  int jrot = (tid & 3) * 4;   // rotation to spread Vt scatter-write banks

  for (int s0 = 0; s0 <= q0; s0 += 64) {
    // ---- stage K row-major, V transposed ----
    const unsigned short* kp = qkv + base + (size_t)(s0 + r0) * RS + D_ + c0;
    us8 k0v = *(const us8*)kp;
    us8 k1v = *(const us8*)(kp + 8);
    const unsigned short* vp = qkv + base + (size_t)(s0 + r0) * RS + 2 * D_ + c0;
    us8 v0v = *(const us8*)vp;
    us8 v1v = *(const us8*)(vp + 8);
    *(us8*)&Ks[r0][c0]     = k0v;
    *(us8*)&Ks[r0][c0 + 8] = k1v;
    unsigned short vv[16];
    *(us8*)&vv[0] = v0v; *(us8*)&vv[8] = v1v;
#pragma unroll
    for (int i = 0; i < 16; ++i) {
      int j = (i + jrot) & 15;
      Vt[c0 + j][r0] = vv[j];
    }
    __syncthreads();

    // ---- QK^T: S[16q x 64s] per wave ----
    f32x4 s_acc[4] = {};
#pragma unroll
    for (int ks = 0; ks < 2; ++ks) {
#pragma unroll
      for (int j = 0; j < 4; ++j) {
        bf16x8 bk = __builtin_bit_cast(bf16x8,
                      *(const us8*)&Ks[j * 16 + lr][ks * 32 + lg * 8]);
        s_acc[j] = __builtin_amdgcn_mfma_f32_16x16x32_bf16(
            qf[ks], bk, s_acc[j], 0, 0, 0);
      }
    }

    // ---- scale + causal mask + online softmax (per row r) ----
#pragma unroll
    for (int r = 0; r < 4; ++r) {
      int qg = q0 + w * 16 + lg * 4 + r;
      float mx = -INFINITY;
#pragma unroll
      for (int j = 0; j < 4; ++j) {
        float sv = s_acc[j][r] * 0.125f;          // 1/sqrt(64)
        int sg = s0 + j * 16 + lr;
        if (sg > qg) sv = -INFINITY;
        s_acc[j][r] = sv;
        mx = fmaxf(mx, sv);
      }
      for (int off = 8; off; off >>= 1) mx = fmaxf(mx, __shfl_xor(mx, off, 64));
      float mnew  = fmaxf(mrow[r], mx);
      float alpha = expf(mrow[r] - mnew);         // first iter: exp(-inf)=0
      float ps = 0.f;
#pragma unroll
      for (int j = 0; j < 4; ++j) {
        float p = expf(s_acc[j][r] - mnew);       // masked -> exp(-inf)=0
        s_acc[j][r] = p;
        ps += p;
      }
      for (int off = 8; off; off >>= 1) ps += __shfl_xor(ps, off, 64);
      lrow[r] = lrow[r] * alpha + ps;
      mrow[r] = mnew;
#pragma unroll
      for (int j = 0; j < 4; ++j) o_acc[j][r] *= alpha;
    }

    // ---- P -> LDS (bf16), wave's own 16 q-rows ----
#pragma unroll
    for (int r = 0; r < 4; ++r)
#pragma unroll
      for (int j = 0; j < 4; ++j)
        Ps[w * 16 + lg * 4 + r][j * 16 + lr] = f2bf(s_acc[j][r]);
    __syncthreads();

    // ---- PV: O[q][d] += P[q][s] V[s][d]; A=Ps (row=q), B=Vt (row=d), k=s ----
#pragma unroll
    for (int ss = 0; ss < 2; ++ss) {
      bf16x8 ap = __builtin_bit_cast(bf16x8,
                    *(const us8*)&Ps[w * 16 + lr][ss * 32 + lg * 8]);
#pragma unroll
      for (int j = 0; j < 4; ++j) {
        bf16x8 bv = __builtin_bit_cast(bf16x8,
                      *(const us8*)&Vt[j * 16 + lr][ss * 32 + lg * 8]);
        o_acc[j] = __builtin_amdgcn_mfma_f32_16x16x32_bf16(
            ap, bv, o_acc[j], 0, 0, 0);
      }
    }
    __syncthreads();
  }

  // ---- epilogue: O / l -> att [BT][D] bf16 ----
#pragma unroll
  for (int r = 0; r < 4; ++r) {
    float inv = 1.f / lrow[r];
    size_t row = (size_t)(b * T_ + q0 + w * 16 + lg * 4 + r) * D_ + h * HD_;
#pragma unroll
    for (int j = 0; j < 4; ++j)
      att[row + j * 16 + lr] = f2bf(o_acc[j][r] * inv);
  }
}

// ---------------------------------------------------------------------------
// launch
// ---------------------------------------------------------------------------
extern "C" void kernel_launch(void* const* d_in, const int* in_sizes, int n_in,
                              void* d_out, int out_size, void* d_ws, size_t ws_size,
                              hipStream_t stream) {
  const int*   idx   = (const int*)  d_in[0];
  const float* tok   = (const float*)d_in[1];
  const float* pos   = (const float*)d_in[2];
  const float* Wq    = (const float*)d_in[3];
  const float* Wk    = (const float*)d_in[4];
  const float* Wv    = (const float*)d_in[5];
  const float* Wp    = (const float*)d_in[6];
  const float* bp    = (const float*)d_in[7];
  const float* ln1g  = (const float*)d_in[8];
  const float* ln1b  = (const float*)d_in[9];
  const float* ln2g  = (const float*)d_in[10];
  const float* ln2b  = (const float*)d_in[11];
  const float* W1    = (const float*)d_in[12];
  const float* b1    = (const float*)d_in[13];
  const float* W2    = (const float*)d_in[14];
  const float* b2    = (const float*)d_in[15];
  const float* lnfg  = (const float*)d_in[16];
  const float* lnfb  = (const float*)d_in[17];
  const float* Wlm   = (const float*)d_in[18];
  const float* blm   = (const float*)d_in[19];
  float* outp = (float*)d_out;

  float* x = (float*)d_ws;
  unsigned short* xn  = (unsigned short*)(x + (size_t)BT_ * D_);
  unsigned short* qkv = xn  + (size_t)BT_ * D_;
  unsigned short* att = qkv + (size_t)BT_ * 3 * D_;
  unsigned short* h1  = att + (size_t)BT_ * D_;
  unsigned short* wt  = h1  + (size_t)BT_ * DFF_;
  unsigned short* wt_qkv = wt;
  unsigned short* wt_p   = wt   + (size_t)3 * D_ * D_;
  unsigned short* wt_1   = wt_p + (size_t)D_ * D_;
  unsigned short* wt_2   = wt_1 + (size_t)D_ * DFF_;

  dim3 blk(256);
  dim3 g_qkv(3 * D_ / GBN, BT_ / GBM);
  dim3 g_d(D_ / GBN, BT_ / GBM);
  dim3 g_ff(DFF_ / GBN, BT_ / GBM);
  dim3 g_lm(V_ / GBN, BT_ / GBM);

  embed_k<<<(BT_ * D_ + 255) / 256, blk, 0, stream>>>(idx, tok, pos, x);

  for (int l = 0; l < L_; ++l) {
    tr_k<<<dim3(D_ / 32, D_ / 32), blk, 0, stream>>>(
        Wq + (size_t)l * D_ * D_, wt_qkv, D_, D_);
    tr_k<<<dim3(D_ / 32, D_ / 32), blk, 0, stream>>>(
        Wk + (size_t)l * D_ * D_, wt_qkv + (size_t)D_ * D_, D_, D_);
    tr_k<<<dim3(D_ / 32, D_ / 32), blk, 0, stream>>>(
        Wv + (size_t)l * D_ * D_, wt_qkv + (size_t)2 * D_ * D_, D_, D_);
    tr_k<<<dim3(D_ / 32, D_ / 32), blk, 0, stream>>>(
        Wp + (size_t)l * D_ * D_, wt_p, D_, D_);
    tr_k<<<dim3(DFF_ / 32, D_ / 32), blk, 0, stream>>>(
        W1 + (size_t)l * D_ * DFF_, wt_1, D_, DFF_);
    tr_k<<<dim3(D_ / 32, DFF_ / 32), blk, 0, stream>>>(
        W2 + (size_t)l * DFF_ * D_, wt_2, DFF_, D_);

    ln_k<<<BT_, blk, 0, stream>>>(x, ln1g + l * D_, ln1b + l * D_, xn);
    gemm_bf<<<g_qkv, blk, 0, stream>>>(xn, wt_qkv, nullptr, nullptr, qkv,
                                       BT_, 3 * D_, D_, 0, 1);
    fattn_k<<<dim3(T_ / 64, H_, B_), blk, 0, stream>>>(qkv, att);
    gemm_bf<<<g_d, blk, 0, stream>>>(att, wt_p, bp + l * D_, x, x,
                                     BT_, D_, D_, 0, 0);

    ln_k<<<BT_, blk, 0, stream>>>(x, ln2g + l * D_, ln2b + l * D_, xn);
    gemm_bf<<<g_ff, blk, 0, stream>>>(xn, wt_1, b1 + l * DFF_, nullptr, h1,
                                      BT_, DFF_, D_, 1, 1);
    gemm_bf<<<g_d, blk, 0, stream>>>(h1, wt_2, b2 + l * D_, x, x,
                                     BT_, D_, DFF_, 0, 0);
  }

  ln_k<<<BT_, blk, 0, stream>>>(x, lnfg, lnfb, xn);
  tr_k<<<dim3(V_ / 32, D_ / 32), blk, 0, stream>>>(Wlm, wt, D_, V_);
  gemm_bf<<<g_lm, blk, 0, stream>>>(xn, wt, blm, nullptr, outp,
                                    BT_, V_, D_, 0, 0);
}